// Round 9
// baseline (94.896 us; speedup 1.0000x reference)
//
#include <hip/hip_runtime.h>
#include <math.h>

#define BB 32
#define TT 2048
#define DD 64
#define PRED 96
#define TP (TT + PRED)      // 2144
#define KTOP 8
// Rare-path margin: covers OUR fp32 FFT ranking error (~1e-6 rel) with 50x
// safety; fires ~8x less than 8e-4 -> cuts the fp64-DFT tail (R8: -3.9 us).
#define MARGIN 1e-4f
#define PI_D 3.14159265358979323846

// bit-reversal helpers/tables
__device__ __forceinline__ int br6(int l) { return (int)(__brev((unsigned)l) >> 26); }
static constexpr int BR4[16] = {0,8,4,12,2,10,6,14,1,9,5,13,3,11,7,15};
// cos/sin(2*pi*j/32), j=0..15 (compile-time twiddles; FFT-16 uses even indices)
static constexpr float C32T[16] = {
    1.0f, 0.98078528040323044913f, 0.92387953251128675613f, 0.83146961230254523708f,
    0.70710678118654752440f, 0.55557023301960222474f, 0.38268343236508977173f, 0.19509032201612826785f,
    0.0f, -0.19509032201612826785f, -0.38268343236508977173f, -0.55557023301960222474f,
    -0.70710678118654752440f, -0.83146961230254523708f, -0.92387953251128675613f, -0.98078528040323044913f};
static constexpr float S32T[16] = {
    0.0f, 0.19509032201612826785f, 0.38268343236508977173f, 0.55557023301960222474f,
    0.70710678118654752440f, 0.83146961230254523708f, 0.92387953251128675613f, 0.98078528040323044913f,
    1.0f, 0.98078528040323044913f, 0.92387953251128675613f, 0.83146961230254523708f,
    0.70710678118654752440f, 0.55557023301960222474f, 0.38268343236508977173f, 0.19509032201612826785f};

// * exp(-2*pi*i*m/2048) via 1-ulp HW trig (revolutions input, exact dyadic)
__device__ __forceinline__ float2 ctw(float2 a, int m) {
    const float rev = (float)m * (1.0f / 2048.0f);
    const float c = __builtin_amdgcn_cosf(rev);
    const float s = __builtin_amdgcn_sinf(rev);
    return make_float2(a.x * c + a.y * s, a.y * c - a.x * s);
}

// POOL float layout (time-multiplexed union, 9216 floats = 36.9 KB):
//   phase 1 (stage-7 exchange): pair*4608 + w*2304 + p*36 + 4c  (max 9211)
//   phase 2 (spectra, overlaid after reads complete):
//     pair*4224 + a (re) / pair*4224 + 2112 + a (im), a = k + (k>>5) skew
//     (max 8446). Extra barrier between read-out and overlay write.
#define SRE(pr,a) POOL[(pr) * 4224 + (a)]
#define SIM(pr,a) POOL[(pr) * 4224 + 2112 + (a)]

// ---------------------------------------------------------------------------
// 512 blocks x 256 threads, now 3 blocks/CU resident (LDS 36.9 KB vs 70.7).
// Identical decomposition/math to R8 (93.6 us): one batch b, 4 channels
// (2 packed signal-pairs) per block; FFT-2048 = in-lane FFT-16 x twiddle x
// cross-lane FFT-128 (stages 1..6 in-wave, stage 7 via one LDS exchange).
// Stage-7 restructured: read partner half to REGISTERS, barrier, then the
// spectrum dump overlays the dead exchange region -> LDS halved -> +50%
// occupancy. Unconfounded test of the occupancy hypothesis (R3's null had
// a decomposition change riding along).
// ---------------------------------------------------------------------------
__global__ __launch_bounds__(256, 3) void fused_kernel(const float* __restrict__ x,
                                                       float* __restrict__ out) {
    __shared__ float POOL[9216];                   // 36.9 KB
    __shared__ int   coefK[4][KTOP];
    __shared__ float coefR[4][KTOP], coefI[4][KTOP];

    const int t    = threadIdx.x;
    const int wv   = t >> 6, p = t & 63;
    const int pair = wv >> 1, w = wv & 1;          // pair 0..1, sig/half w 0..1
    // XCD swizzle: grp4 quads (one 64B output line) + input lines same XCD.
    const int bid  = blockIdx.x;
    const int xcd  = bid & 7;
    const int idx  = bid >> 3;                     // 0..63
    const int b    = (idx >> 3) * 4 + (xcd >> 1);  // 0..31
    const int grp4 = (xcd & 1) * 8 + (idx & 7);    // 0..15: 4-channel group
    const int dp   = grp4 * 2 + pair;              // float2 pair 0..31
    const int ch   = grp4 * 4 + wv;                // this wave's channel 0..63

    const float2* xv = (const float2*)x;
    const size_t xbase = (size_t)b * TT * (DD / 2) + dp;
    const int rl = 2 * br6(p) + w;                 // = br7(64*w + p)

    // ---- load: v[i] = x[n = 128*BR4[i] + rl] (both reversals folded in) ----
    float2 v[16];
    #pragma unroll
    for (int i = 0; i < 16; ++i)
        v[i] = xv[xbase + (size_t)(128 * BR4[i] + rl) * (DD / 2)];

    // ---- in-lane FFT-16 (DIT, natural-order output, constant twiddles) ----
    #pragma unroll
    for (int s = 1; s <= 4; ++s) {
        const int m = 1 << s, half = m >> 1, stepw = 32 >> s;
        #pragma unroll
        for (int g = 0; g < 16; g += m) {
            #pragma unroll
            for (int j = 0; j < half; ++j) {
                const float c = C32T[j * stepw], sn = S32T[j * stepw];
                const int i0 = g + j, i1 = i0 + half;
                const float tr = c * v[i1].x + sn * v[i1].y;
                const float ti = c * v[i1].y - sn * v[i1].x;
                v[i1] = make_float2(v[i0].x - tr, v[i0].y - ti);
                v[i0] = make_float2(v[i0].x + tr, v[i0].y + ti);
            }
        }
    }

    // ---- twiddle: v[q] *= W2048^(rl*q) (rl = subsequence index) ----
    #pragma unroll
    for (int q = 1; q < 16; ++q) v[q] = ctw(v[q], (rl * q) & (TT - 1));

    // ---- cross-lane FFT-128, stages 1..6 (in-wave xor shuffles) ----
    #pragma unroll
    for (int s = 1; s <= 6; ++s) {
        const int half = 1 << (s - 1);
        const float rev = (float)(p & (half - 1)) / (float)(1 << s);
        const float wc  = __builtin_amdgcn_cosf(rev);
        const float wsn = __builtin_amdgcn_sinf(rev);
        const bool  hi  = (p & half) != 0;
        #pragma unroll
        for (int q = 0; q < 16; ++q) {
            float2 pv;
            pv.x = __shfl_xor(v[q].x, half, 64);
            pv.y = __shfl_xor(v[q].y, half, 64);
            const float2 bsv = hi ? v[q] : pv;
            const float2 asv = hi ? pv : v[q];
            const float tr = wc * bsv.x + wsn * bsv.y;
            const float ti = wc * bsv.y - wsn * bsv.x;
            v[q] = hi ? make_float2(asv.x - tr, asv.y - ti)
                      : make_float2(asv.x + tr, asv.y + ti);
        }
    }

    // ---- stage 7 (distance 64 = cross-wave) via LDS, reads staged to regs --
    {
        const int exw = pair * 4608 + w * 2304 + p * 36;
        #pragma unroll
        for (int c = 0; c < 8; ++c)
            *(float4*)&POOL[exw + 4 * c] =
                make_float4(v[2*c].x, v[2*c].y, v[2*c+1].x, v[2*c+1].y);
    }
    __syncthreads();                               // partner's half visible
    float4 g[8];                                   // partner data -> registers
    {
        const int exr = pair * 4608 + (1 - w) * 2304 + p * 36;
        #pragma unroll
        for (int c = 0; c < 8; ++c)
            g[c] = *(const float4*)&POOL[exr + 4 * c];
    }
    __syncthreads();                               // ALL reads done; exchange dead

    // ---- butterfly + spectrum dump overlaid on the exchange region ----
    {
        const float revp = (float)p * (1.0f / 128.0f);
        const float wc7 = __builtin_amdgcn_cosf(revp);
        const float ws7 = __builtin_amdgcn_sinf(revp);
        const int kb = 1024 * w + 16 * p;          // this lane's k base
        #pragma unroll
        for (int c = 0; c < 8; ++c) {
            #pragma unroll
            for (int e = 0; e < 2; ++e) {
                const int q = 2 * c + e;
                const float2 pv = e ? make_float2(g[c].z, g[c].w)
                                    : make_float2(g[c].x, g[c].y);
                const float2 bsv = w ? v[q] : pv;  // hi-half (w=1) operand
                const float2 asv = w ? pv : v[q];
                const float tr = wc7 * bsv.x + ws7 * bsv.y;
                const float ti = wc7 * bsv.y - ws7 * bsv.x;
                const int k = kb + q, a = k + (k >> 5);
                SRE(pair, a) = w ? (asv.x - tr) : (asv.x + tr);
                SIM(pair, a) = w ? (asv.y - ti) : (asv.y + ti);
            }
        }
    }
    __syncthreads();                               // full pair spectrum ready

    // ======== selection: one wave per channel, 16 keys/lane ========
    unsigned A[16];
    #pragma unroll
    for (int q = 0; q < 16; ++q) {
        const int k = 16 * p + q;                  // 0..1023
        unsigned kk = 0u;
        if (k != 0) {
            const int a1 = k + (k >> 5);
            const int pk = TT - k, a2 = pk + (pk >> 5);
            const float zr = SRE(pair, a1), zi = SIM(pair, a1);
            const float yr = SRE(pair, a2), yi = SIM(pair, a2);
            float cr, ci;
            if (w == 0) { cr = 0.5f * (zr + yr); ci = 0.5f * (zi - yi); }
            else        { cr = 0.5f * (zi + yi); ci = 0.5f * (yr - zr); }
            const float mg = cr * cr + ci * ci;
            kk = (__float_as_uint(mg) & 0xFFFFF800u) | (unsigned)(2047 - k);
        }
        A[q] = kk;
    }

    // in-register bitonic sort-16, descending
    #pragma unroll
    for (int sz = 2; sz <= 16; sz <<= 1) {
        #pragma unroll
        for (int d = sz >> 1; d > 0; d >>= 1) {
            #pragma unroll
            for (int i2 = 0; i2 < 16; ++i2) {
                const int j2i = i2 ^ d;
                if (j2i > i2) {
                    const bool desc = ((i2 & sz) == 0);
                    const unsigned a = A[i2], b2 = A[j2i];
                    const unsigned mx = a > b2 ? a : b2, mn = a > b2 ? b2 : a;
                    A[i2] = desc ? mx : mn;  A[j2i] = desc ? mn : mx;
                }
            }
        }
    }
    // 6 truncated XOR-merge stages across 64 lanes -> global top-16
    #pragma unroll
    for (int off = 1; off <= 32; off <<= 1) {
        unsigned Bv[16];
        #pragma unroll
        for (int i2 = 0; i2 < 16; ++i2)
            Bv[i2] = (unsigned)__shfl_xor((int)A[i2], off, 64);
        #pragma unroll
        for (int i2 = 0; i2 < 16; ++i2) {
            const unsigned o = Bv[15 - i2];
            A[i2] = A[i2] > o ? A[i2] : o;         // top-16 multiset, bitonic
        }
        #pragma unroll
        for (int d = 8; d > 0; d >>= 1) {
            #pragma unroll
            for (int i2 = 0; i2 < 16; ++i2) {
                if ((i2 & d) == 0) {
                    const int j2i = i2 + d;
                    const unsigned a = A[i2], b2 = A[j2i];
                    A[i2] = a > b2 ? a : b2;  A[j2i] = a > b2 ? b2 : a;
                }
            }
        }
    }
    // every lane: sorted top-16 of this wave's channel

    const float m8f = __uint_as_float(A[7] & 0xFFFFF800u);
    unsigned bandmask = 0u;
    #pragma unroll
    for (int r = 0; r < 16; ++r) {
        const float mr = __uint_as_float(A[r] & 0xFFFFF800u);
        if (fabsf(mr - m8f) <= MARGIN * m8f) bandmask |= (1u << r);
    }
    const int flg = (bandmask != (1u << 7)) ? 1 : 0;   // wave-uniform

    unsigned myk = 0u;                                 // candidate p (p<16)
    #pragma unroll
    for (int i2 = 0; i2 < 16; ++i2) myk = (p == i2) ? A[i2] : myk;
    const int kcand = 2047 - (int)(myk & 0x7FFu);

    if (!flg && p < KTOP) {
        const int k = kcand, a1 = k + (k >> 5), pk = TT - k, a2 = pk + (pk >> 5);
        const float zr = SRE(pair, a1), zi = SIM(pair, a1);
        const float yr = SRE(pair, a2), yi = SIM(pair, a2);
        float cr, ci;
        if (w == 0) { cr = 0.5f * (zr + yr); ci = 0.5f * (zi - yi); }
        else        { cr = 0.5f * (zi + yi); ci = 0.5f * (yr - zr); }
        coefK[wv][p] = k;
        coefR[wv][p] = cr * (2.0f / (float)TT);
        coefI[wv][p] = ci * (2.0f / (float)TT);
    }

    // ---- rare path: fp64 DFT of band members, exact re-rank + splice ----
    if (flg) {
        float sv[32];
        const float* xs = x + (size_t)b * TT * DD + ch;
        #pragma unroll
        for (int m2 = 0; m2 < 32; ++m2)
            sv[m2] = xs[(size_t)(p + 64 * m2) * DD];
        const double thA = -2.0 * PI_D * (double)p / 64.0;
        const double thB = -2.0 * PI_D * (double)p / (double)TT;
        const double wac = cos(thA), was = sin(thA);
        const double wbc = cos(thB), wbs = sin(thB);

        const unsigned bm = bandmask;              // uniform across wave
        const int lo = (int)__builtin_ctz(bm);
        double myM = 0.0, myR = 0.0, myI = 0.0;
        for (int r = 0; r < 16; ++r) {
            if (!((bm >> r) & 1u)) continue;       // wave-uniform
            const int kr = __shfl(kcand, r, 64);
            double ar = 0.0, ai = 0.0;
            for (int m2 = 0; m2 < 32; ++m2) {
                const int n  = p + 64 * m2;
                const int mm = (n * kr) & (TT - 1);
                const double qc  = __shfl(wac, mm >> 5, 64);
                const double qs  = __shfl(was, mm >> 5, 64);
                const double rc2 = __shfl(wbc, mm & 31, 64);
                const double rs2 = __shfl(wbs, mm & 31, 64);
                const double wr = qc * rc2 - qs * rs2;
                const double wi = qc * rs2 + qs * rc2;
                ar = fma((double)sv[m2], wr, ar);
                ai = fma((double)sv[m2], wi, ai);
            }
            #pragma unroll
            for (int off = 32; off; off >>= 1) {
                ar += __shfl_xor(ar, off, 64);
                ai += __shfl_xor(ai, off, 64);
            }
            if (p == r) { myM = ar * ar + ai * ai; myR = ar; myI = ai; }
        }
        // rank on ALL lanes (shuffles fully active), write on lanes < 16
        const int h16 = p & 15;
        const double selfM = __shfl(myM, h16, 64);
        const int    selfK = __shfl(kcand, h16, 64);
        int rb = 0;
        for (int r2 = 0; r2 < 16; ++r2) {
            if (!((bm >> r2) & 1u)) continue;
            const double om = __shfl(myM, r2, 64);
            const int    ok = __shfl(kcand, r2, 64);
            if (r2 != h16 && (om > selfM || (om == selfM && ok < selfK))) ++rb;
        }
        const int isband = (int)((bm >> h16) & 1u);
        const int rank = isband ? (lo + rb) : h16;
        if (p < 16 && rank < KTOP) {
            coefK[wv][rank] = kcand;
            if (isband) {
                coefR[wv][rank] = (float)(myR * (2.0 / (double)TT));
                coefI[wv][rank] = (float)(myI * (2.0 / (double)TT));
            } else {
                const int k = kcand, a1 = k + (k >> 5), pk = TT - k, a2 = pk + (pk >> 5);
                const float zr = SRE(pair, a1), zi = SIM(pair, a1);
                const float yr = SRE(pair, a2), yi = SIM(pair, a2);
                float cr, ci;
                if (w == 0) { cr = 0.5f * (zr + yr); ci = 0.5f * (zi - yi); }
                else        { cr = 0.5f * (zi + yi); ci = 0.5f * (yr - zr); }
                coefR[wv][rank] = cr * (2.0f / (float)TT);
                coefI[wv][rank] = ci * (2.0f / (float)TT);
            }
        }
    }
    __syncthreads();   // all 4 channels' coefs ready

    // ======== synthesis: phasor rotation, DIRECT global stores ========
    // thread -> (d4 = t&3, tq = t>>2 in [0,64)); tv = tq + 64*m, m = 0..33
    const int d4 = t & 3, tq = t >> 2;
    int   kc[KTOP];
    float fr[KTOP], fi[KTOP], pc[KTOP], ps[KTOP], rc[KTOP], rs[KTOP];
    #pragma unroll
    for (int pp = 0; pp < KTOP; ++pp) {
        kc[pp] = coefK[d4][pp];
        fr[pp] = coefR[d4][pp];
        fi[pp] = coefI[d4][pp];
        const int j0 = (kc[pp] * tq) & (TT - 1);
        const float rv0 = (float)j0 * (1.0f / 2048.0f);
        pc[pp] = __builtin_amdgcn_cosf(rv0);
        ps[pp] = __builtin_amdgcn_sinf(rv0);
        const int jr = (kc[pp] * 64) & (TT - 1);
        const float rvr = (float)jr * (1.0f / 2048.0f);
        rc[pp] = __builtin_amdgcn_cosf(rvr);
        rs[pp] = __builtin_amdgcn_sinf(rvr);
    }
    float* ob = out + (size_t)b * TP * DD + grp4 * 4 + d4;
    #pragma unroll 2
    for (int m = 0; m < 34; ++m) {                 // 33*64 + 32 = 2144 = TP
        const int tv = tq + 64 * m;
        float acc = 0.0f;
        #pragma unroll
        for (int pp = 0; pp < KTOP; ++pp) acc += fr[pp] * pc[pp] - fi[pp] * ps[pp];
        if (tv < TP) ob[(size_t)tv * DD] = acc;
        #pragma unroll
        for (int pp = 0; pp < KTOP; ++pp) {
            const float nc = pc[pp] * rc[pp] - ps[pp] * rs[pp];
            const float ns = pc[pp] * rs[pp] + ps[pp] * rc[pp];
            pc[pp] = nc; ps[pp] = ns;
        }
    }
}

extern "C" void kernel_launch(void* const* d_in, const int* in_sizes, int n_in,
                              void* d_out, int out_size, void* d_ws, size_t ws_size,
                              hipStream_t stream) {
    const float* x = (const float*)d_in[0];
    float* out = (float*)d_out;
    (void)d_ws; (void)ws_size; (void)in_sizes; (void)n_in; (void)out_size;

    fused_kernel<<<BB * 16, 256, 0, stream>>>(x, out);
}

// Round 10
// 92.472 us; speedup vs baseline: 1.0262x; 1.0262x over previous
//
#include <hip/hip_runtime.h>
#include <math.h>

#define BB 32
#define TT 2048
#define DD 64
#define PRED 96
#define TP (TT + PRED)      // 2144
#define KTOP 8
// Rare-path margin: covers OUR fp32 FFT ranking error (~1e-6 rel) with 50x
// safety; fires ~8x less than 8e-4 -> cuts the fp64-DFT tail (R8: -3.9 us).
#define MARGIN 1e-4f
#define PI_D 3.14159265358979323846

// bit-reversal helpers/tables
__device__ __forceinline__ int br6(int l) { return (int)(__brev((unsigned)l) >> 26); }
static constexpr int BR4[16] = {0,8,4,12,2,10,6,14,1,9,5,13,3,11,7,15};
// cos/sin(2*pi*j/32), j=0..15 (compile-time twiddles; FFT-16 uses even indices)
static constexpr float C32T[16] = {
    1.0f, 0.98078528040323044913f, 0.92387953251128675613f, 0.83146961230254523708f,
    0.70710678118654752440f, 0.55557023301960222474f, 0.38268343236508977173f, 0.19509032201612826785f,
    0.0f, -0.19509032201612826785f, -0.38268343236508977173f, -0.55557023301960222474f,
    -0.70710678118654752440f, -0.83146961230254523708f, -0.92387953251128675613f, -0.98078528040323044913f};
static constexpr float S32T[16] = {
    0.0f, 0.19509032201612826785f, 0.38268343236508977173f, 0.55557023301960222474f,
    0.70710678118654752440f, 0.83146961230254523708f, 0.92387953251128675613f, 0.98078528040323044913f,
    1.0f, 0.98078528040323044913f, 0.92387953251128675613f, 0.83146961230254523708f,
    0.70710678118654752440f, 0.55557023301960222474f, 0.38268343236508977173f, 0.19509032201612826785f};

// * exp(-2*pi*i*m/2048) via 1-ulp HW trig (revolutions input, exact dyadic)
__device__ __forceinline__ float2 ctw(float2 a, int m) {
    const float rev = (float)m * (1.0f / 2048.0f);
    const float c = __builtin_amdgcn_cosf(rev);
    const float s = __builtin_amdgcn_sinf(rev);
    return make_float2(a.x * c + a.y * s, a.y * c - a.x * s);
}

// POOL float layout:
//   [0, 4352)     : load staging (pair-1 halves), w*2176 + p*34 + 2i
//                   (stride 34 -> banks (2p+2i)%32, b64-aligned; DEAD before
//                   the stage-7 exchange overlays it, barrier-separated)
//   [0, 9216)     : stage-7 cross-wave exchange, pair*4608 + w*2304 + p*36 + 4c
//   [9216, 17664) : spectra, pair*4224 + a (re) / +2112 (im), a = k + (k>>5)
#define SG(wi,pi,ii) POOL[(wi) * 2176 + (pi) * 34 + 2 * (ii)]
#define SRE(pr,a) POOL[9216 + (pr) * 4224 + (a)]
#define SIM(pr,a) POOL[9216 + (pr) * 4224 + 2112 + (a)]

// ---------------------------------------------------------------------------
// 512 blocks x 256 threads (2 blocks/CU: the measured-best residency).
// Identical math to R8 (93.6 us). ONE change: the gather front-end.
// Waves (pair,w) 0=(0,0),1=(0,1),2=(1,0),3=(1,1): waves 0,2 load identical
// row sets (rl = 2*br6(p)+w is pair-independent) from adjacent float2
// columns. So waves 0,1 load float4 (both pairs at once), keep .xy, stage
// .zw in LDS for waves 2,3 -> gather wave-instructions halve (64 -> 32 per
// block), halving TA line transactions (the only positively-measured lever
// left: R6 showed full coalescing saved ~3.5 us on the fused kernel).
// ---------------------------------------------------------------------------
__global__ __launch_bounds__(256, 2) void fused_kernel(const float* __restrict__ x,
                                                       float* __restrict__ out) {
    __shared__ float POOL[17664];                  // 70.7 KB
    __shared__ int   coefK[4][KTOP];
    __shared__ float coefR[4][KTOP], coefI[4][KTOP];

    const int t    = threadIdx.x;
    const int wv   = t >> 6, p = t & 63;
    const int pair = wv >> 1, w = wv & 1;          // pair 0..1, sig/half w 0..1
    // XCD swizzle: grp4 quads (one 64B output line) + input lines same XCD.
    const int bid  = blockIdx.x;
    const int xcd  = bid & 7;
    const int idx  = bid >> 3;                     // 0..63
    const int b    = (idx >> 3) * 4 + (xcd >> 1);  // 0..31
    const int grp4 = (xcd & 1) * 8 + (idx & 7);    // 0..15: 4-channel group
    const int dp   = grp4 * 2 + pair;              // float2 pair 0..31
    const int ch   = grp4 * 4 + wv;                // this wave's channel 0..63

    const int rl = 2 * br6(p) + w;                 // = br7(64*w + p)

    // ---- gather: waves 0,1 load float4 (pairs 0+1), stage pair-1 halves ----
    float2 v[16];
    if (wv < 2) {                                  // wv==w here (pair==0)
        const float4* xq = (const float4*)x;       // 16 float4 per row
        const size_t rowbase = (size_t)b * TT;
        #pragma unroll
        for (int i = 0; i < 16; ++i) {
            const int n = 128 * BR4[i] + rl;
            const float4 f = xq[(rowbase + (size_t)n) * 16 + grp4];
            v[i] = make_float2(f.x, f.y);          // pair 0 (own)
            *(float2*)&SG(wv, p, i) = make_float2(f.z, f.w);   // pair 1
        }
    }
    __syncthreads();                               // staging visible
    if (wv >= 2) {
        #pragma unroll
        for (int i = 0; i < 16; ++i)
            v[i] = *(const float2*)&SG(w, p, i);
    }
    __syncthreads();                               // staging dead; POOL reusable

    // ---- in-lane FFT-16 (DIT, natural-order output, constant twiddles) ----
    #pragma unroll
    for (int s = 1; s <= 4; ++s) {
        const int m = 1 << s, half = m >> 1, stepw = 32 >> s;
        #pragma unroll
        for (int g = 0; g < 16; g += m) {
            #pragma unroll
            for (int j = 0; j < half; ++j) {
                const float c = C32T[j * stepw], sn = S32T[j * stepw];
                const int i0 = g + j, i1 = i0 + half;
                const float tr = c * v[i1].x + sn * v[i1].y;
                const float ti = c * v[i1].y - sn * v[i1].x;
                v[i1] = make_float2(v[i0].x - tr, v[i0].y - ti);
                v[i0] = make_float2(v[i0].x + tr, v[i0].y + ti);
            }
        }
    }

    // ---- twiddle: v[q] *= W2048^(rl*q) (rl = subsequence index) ----
    #pragma unroll
    for (int q = 1; q < 16; ++q) v[q] = ctw(v[q], (rl * q) & (TT - 1));

    // ---- cross-lane FFT-128, stages 1..6 (in-wave xor shuffles) ----
    #pragma unroll
    for (int s = 1; s <= 6; ++s) {
        const int half = 1 << (s - 1);
        const float rev = (float)(p & (half - 1)) / (float)(1 << s);
        const float wc  = __builtin_amdgcn_cosf(rev);
        const float wsn = __builtin_amdgcn_sinf(rev);
        const bool  hi  = (p & half) != 0;
        #pragma unroll
        for (int q = 0; q < 16; ++q) {
            float2 pv;
            pv.x = __shfl_xor(v[q].x, half, 64);
            pv.y = __shfl_xor(v[q].y, half, 64);
            const float2 bsv = hi ? v[q] : pv;
            const float2 asv = hi ? pv : v[q];
            const float tr = wc * bsv.x + wsn * bsv.y;
            const float ti = wc * bsv.y - wsn * bsv.x;
            v[q] = hi ? make_float2(asv.x - tr, asv.y - ti)
                      : make_float2(asv.x + tr, asv.y + ti);
        }
    }

    // ---- stage 7 (distance 64 = cross-wave) via LDS + fused spectrum dump --
    {
        const int exw = pair * 4608 + w * 2304 + p * 36;
        #pragma unroll
        for (int c = 0; c < 8; ++c)
            *(float4*)&POOL[exw + 4 * c] =
                make_float4(v[2*c].x, v[2*c].y, v[2*c+1].x, v[2*c+1].y);
    }
    __syncthreads();                               // partner's half visible
    {
        const int exr = pair * 4608 + (1 - w) * 2304 + p * 36;
        const float revp = (float)p * (1.0f / 128.0f);
        const float wc7 = __builtin_amdgcn_cosf(revp);
        const float ws7 = __builtin_amdgcn_sinf(revp);
        const int kb = 1024 * w + 16 * p;          // this lane's k base
        #pragma unroll
        for (int c = 0; c < 8; ++c) {
            const float4 g = *(const float4*)&POOL[exr + 4 * c];
            #pragma unroll
            for (int e = 0; e < 2; ++e) {
                const int q = 2 * c + e;
                const float2 pv = e ? make_float2(g.z, g.w) : make_float2(g.x, g.y);
                const float2 bsv = w ? v[q] : pv;  // hi-half (w=1) operand
                const float2 asv = w ? pv : v[q];
                const float tr = wc7 * bsv.x + ws7 * bsv.y;
                const float ti = wc7 * bsv.y - ws7 * bsv.x;
                const int k = kb + q, a = k + (k >> 5);
                SRE(pair, a) = w ? (asv.x - tr) : (asv.x + tr);
                SIM(pair, a) = w ? (asv.y - ti) : (asv.y + ti);
            }
        }
    }
    __syncthreads();                               // full pair spectrum ready

    // ======== selection: one wave per channel, 16 keys/lane ========
    unsigned A[16];
    #pragma unroll
    for (int q = 0; q < 16; ++q) {
        const int k = 16 * p + q;                  // 0..1023
        unsigned kk = 0u;
        if (k != 0) {
            const int a1 = k + (k >> 5);
            const int pk = TT - k, a2 = pk + (pk >> 5);
            const float zr = SRE(pair, a1), zi = SIM(pair, a1);
            const float yr = SRE(pair, a2), yi = SIM(pair, a2);
            float cr, ci;
            if (w == 0) { cr = 0.5f * (zr + yr); ci = 0.5f * (zi - yi); }
            else        { cr = 0.5f * (zi + yi); ci = 0.5f * (yr - zr); }
            const float mg = cr * cr + ci * ci;
            kk = (__float_as_uint(mg) & 0xFFFFF800u) | (unsigned)(2047 - k);
        }
        A[q] = kk;
    }

    // in-register bitonic sort-16, descending
    #pragma unroll
    for (int sz = 2; sz <= 16; sz <<= 1) {
        #pragma unroll
        for (int d = sz >> 1; d > 0; d >>= 1) {
            #pragma unroll
            for (int i2 = 0; i2 < 16; ++i2) {
                const int j2i = i2 ^ d;
                if (j2i > i2) {
                    const bool desc = ((i2 & sz) == 0);
                    const unsigned a = A[i2], b2 = A[j2i];
                    const unsigned mx = a > b2 ? a : b2, mn = a > b2 ? b2 : a;
                    A[i2] = desc ? mx : mn;  A[j2i] = desc ? mn : mx;
                }
            }
        }
    }
    // 6 truncated XOR-merge stages across 64 lanes -> global top-16
    #pragma unroll
    for (int off = 1; off <= 32; off <<= 1) {
        unsigned Bv[16];
        #pragma unroll
        for (int i2 = 0; i2 < 16; ++i2)
            Bv[i2] = (unsigned)__shfl_xor((int)A[i2], off, 64);
        #pragma unroll
        for (int i2 = 0; i2 < 16; ++i2) {
            const unsigned o = Bv[15 - i2];
            A[i2] = A[i2] > o ? A[i2] : o;         // top-16 multiset, bitonic
        }
        #pragma unroll
        for (int d = 8; d > 0; d >>= 1) {
            #pragma unroll
            for (int i2 = 0; i2 < 16; ++i2) {
                if ((i2 & d) == 0) {
                    const int j2i = i2 + d;
                    const unsigned a = A[i2], b2 = A[j2i];
                    A[i2] = a > b2 ? a : b2;  A[j2i] = a > b2 ? b2 : a;
                }
            }
        }
    }
    // every lane: sorted top-16 of this wave's channel

    const float m8f = __uint_as_float(A[7] & 0xFFFFF800u);
    unsigned bandmask = 0u;
    #pragma unroll
    for (int r = 0; r < 16; ++r) {
        const float mr = __uint_as_float(A[r] & 0xFFFFF800u);
        if (fabsf(mr - m8f) <= MARGIN * m8f) bandmask |= (1u << r);
    }
    const int flg = (bandmask != (1u << 7)) ? 1 : 0;   // wave-uniform

    unsigned myk = 0u;                                 // candidate p (p<16)
    #pragma unroll
    for (int i2 = 0; i2 < 16; ++i2) myk = (p == i2) ? A[i2] : myk;
    const int kcand = 2047 - (int)(myk & 0x7FFu);

    if (!flg && p < KTOP) {
        const int k = kcand, a1 = k + (k >> 5), pk = TT - k, a2 = pk + (pk >> 5);
        const float zr = SRE(pair, a1), zi = SIM(pair, a1);
        const float yr = SRE(pair, a2), yi = SIM(pair, a2);
        float cr, ci;
        if (w == 0) { cr = 0.5f * (zr + yr); ci = 0.5f * (zi - yi); }
        else        { cr = 0.5f * (zi + yi); ci = 0.5f * (yr - zr); }
        coefK[wv][p] = k;
        coefR[wv][p] = cr * (2.0f / (float)TT);
        coefI[wv][p] = ci * (2.0f / (float)TT);
    }

    // ---- rare path: fp64 DFT of band members, exact re-rank + splice ----
    if (flg) {
        float sv[32];
        const float* xs = x + (size_t)b * TT * DD + ch;
        #pragma unroll
        for (int m2 = 0; m2 < 32; ++m2)
            sv[m2] = xs[(size_t)(p + 64 * m2) * DD];
        const double thA = -2.0 * PI_D * (double)p / 64.0;
        const double thB = -2.0 * PI_D * (double)p / (double)TT;
        const double wac = cos(thA), was = sin(thA);
        const double wbc = cos(thB), wbs = sin(thB);

        const unsigned bm = bandmask;              // uniform across wave
        const int lo = (int)__builtin_ctz(bm);
        double myM = 0.0, myR = 0.0, myI = 0.0;
        for (int r = 0; r < 16; ++r) {
            if (!((bm >> r) & 1u)) continue;       // wave-uniform
            const int kr = __shfl(kcand, r, 64);
            double ar = 0.0, ai = 0.0;
            for (int m2 = 0; m2 < 32; ++m2) {
                const int n  = p + 64 * m2;
                const int mm = (n * kr) & (TT - 1);
                const double qc  = __shfl(wac, mm >> 5, 64);
                const double qs  = __shfl(was, mm >> 5, 64);
                const double rc2 = __shfl(wbc, mm & 31, 64);
                const double rs2 = __shfl(wbs, mm & 31, 64);
                const double wr = qc * rc2 - qs * rs2;
                const double wi = qc * rs2 + qs * rc2;
                ar = fma((double)sv[m2], wr, ar);
                ai = fma((double)sv[m2], wi, ai);
            }
            #pragma unroll
            for (int off = 32; off; off >>= 1) {
                ar += __shfl_xor(ar, off, 64);
                ai += __shfl_xor(ai, off, 64);
            }
            if (p == r) { myM = ar * ar + ai * ai; myR = ar; myI = ai; }
        }
        // rank on ALL lanes (shuffles fully active), write on lanes < 16
        const int h16 = p & 15;
        const double selfM = __shfl(myM, h16, 64);
        const int    selfK = __shfl(kcand, h16, 64);
        int rb = 0;
        for (int r2 = 0; r2 < 16; ++r2) {
            if (!((bm >> r2) & 1u)) continue;
            const double om = __shfl(myM, r2, 64);
            const int    ok = __shfl(kcand, r2, 64);
            if (r2 != h16 && (om > selfM || (om == selfM && ok < selfK))) ++rb;
        }
        const int isband = (int)((bm >> h16) & 1u);
        const int rank = isband ? (lo + rb) : h16;
        if (p < 16 && rank < KTOP) {
            coefK[wv][rank] = kcand;
            if (isband) {
                coefR[wv][rank] = (float)(myR * (2.0 / (double)TT));
                coefI[wv][rank] = (float)(myI * (2.0 / (double)TT));
            } else {
                const int k = kcand, a1 = k + (k >> 5), pk = TT - k, a2 = pk + (pk >> 5);
                const float zr = SRE(pair, a1), zi = SIM(pair, a1);
                const float yr = SRE(pair, a2), yi = SIM(pair, a2);
                float cr, ci;
                if (w == 0) { cr = 0.5f * (zr + yr); ci = 0.5f * (zi - yi); }
                else        { cr = 0.5f * (zi + yi); ci = 0.5f * (yr - zr); }
                coefR[wv][rank] = cr * (2.0f / (float)TT);
                coefI[wv][rank] = ci * (2.0f / (float)TT);
            }
        }
    }
    __syncthreads();   // all 4 channels' coefs ready

    // ======== synthesis: phasor rotation, DIRECT global stores ========
    // thread -> (d4 = t&3, tq = t>>2 in [0,64)); tv = tq + 64*m, m = 0..33
    const int d4 = t & 3, tq = t >> 2;
    int   kc[KTOP];
    float fr[KTOP], fi[KTOP], pc[KTOP], ps[KTOP], rc[KTOP], rs[KTOP];
    #pragma unroll
    for (int pp = 0; pp < KTOP; ++pp) {
        kc[pp] = coefK[d4][pp];
        fr[pp] = coefR[d4][pp];
        fi[pp] = coefI[d4][pp];
        const int j0 = (kc[pp] * tq) & (TT - 1);
        const float rv0 = (float)j0 * (1.0f / 2048.0f);
        pc[pp] = __builtin_amdgcn_cosf(rv0);
        ps[pp] = __builtin_amdgcn_sinf(rv0);
        const int jr = (kc[pp] * 64) & (TT - 1);
        const float rvr = (float)jr * (1.0f / 2048.0f);
        rc[pp] = __builtin_amdgcn_cosf(rvr);
        rs[pp] = __builtin_amdgcn_sinf(rvr);
    }
    float* ob = out + (size_t)b * TP * DD + grp4 * 4 + d4;
    #pragma unroll 2
    for (int m = 0; m < 34; ++m) {                 // 33*64 + 32 = 2144 = TP
        const int tv = tq + 64 * m;
        float acc = 0.0f;
        #pragma unroll
        for (int pp = 0; pp < KTOP; ++pp) acc += fr[pp] * pc[pp] - fi[pp] * ps[pp];
        if (tv < TP) ob[(size_t)tv * DD] = acc;
        #pragma unroll
        for (int pp = 0; pp < KTOP; ++pp) {
            const float nc = pc[pp] * rc[pp] - ps[pp] * rs[pp];
            const float ns = pc[pp] * rs[pp] + ps[pp] * rc[pp];
            pc[pp] = nc; ps[pp] = ns;
        }
    }
}

extern "C" void kernel_launch(void* const* d_in, const int* in_sizes, int n_in,
                              void* d_out, int out_size, void* d_ws, size_t ws_size,
                              hipStream_t stream) {
    const float* x = (const float*)d_in[0];
    float* out = (float*)d_out;
    (void)d_ws; (void)ws_size; (void)in_sizes; (void)n_in; (void)out_size;

    fused_kernel<<<BB * 16, 256, 0, stream>>>(x, out);
}